// Round 3
// baseline (2028.664 us; speedup 1.0000x reference)
//
#include <hip/hip_runtime.h>

#define NN   100000
#define NE   1600000
#define FE   16
#define HID  64
#define MID  128
#define CAT  256
#define LEAK 0.01f
#define BNE  1e-5f

typedef float4 f4;

__device__ __forceinline__ float lrelu(float v){ return v >= 0.f ? v : LEAK * v; }

// ---- copy x into xs[:, 0:64] (xs row stride 256 floats) ----
__global__ void __launch_bounds__(256) k_copy_x(const f4* __restrict__ x4, f4* __restrict__ xs4){
    int idx = blockIdx.x * 256 + threadIdx.x;            // over NN*16 float4s
    if (idx >= NN * 16) return;
    int n = idx >> 4, j = idx & 15;
    xs4[n * 64 + j] = x4[idx];
}

// ---- edge message + scatter-add: agg[dst] += relu(h[src] + ea@We + be) ----
// wave per edge, lane = output feature; We column in registers
__global__ void __launch_bounds__(256) k_edge(const float* __restrict__ h,
        const int* __restrict__ ei, const f4* __restrict__ ea4,
        const float* __restrict__ We, const float* __restrict__ be,
        float* __restrict__ agg){
    const int lane = threadIdx.x & 63;
    float w[FE];
    #pragma unroll
    for (int k = 0; k < FE; ++k) w[k] = We[k * HID + lane];
    const float bv = be[lane];
    const int nw = (gridDim.x * 256) >> 6;
    for (int e = (blockIdx.x * 256 + threadIdx.x) >> 6; e < NE; e += nw){
        int src = ei[e], dst = ei[NE + e];
        float acc = bv;
        #pragma unroll
        for (int q = 0; q < 4; ++q){
            f4 v = ea4[e * 4 + q];
            acc = fmaf(v.x, w[q * 4 + 0], acc);
            acc = fmaf(v.y, w[q * 4 + 1], acc);
            acc = fmaf(v.z, w[q * 4 + 2], acc);
            acc = fmaf(v.w, w[q * 4 + 3], acc);
        }
        float msg = fmaxf(h[src * CAT + lane] + acc, 0.f);
        atomicAdd(&agg[dst * HID + lane], msg);
    }
}

// ---- z1 = ((1+eps)*h + agg) @ W1 + b1, accumulate BN stats ----
__global__ void __launch_bounds__(256) k_mm1(const float* __restrict__ h,
        const float* __restrict__ agg, const float* __restrict__ eps, int li,
        const float* __restrict__ W, const float* __restrict__ b,
        float* __restrict__ z1, float* __restrict__ stats){
    __shared__ float Ws[HID * HID];
    __shared__ float red[2][4][HID];
    for (int j = threadIdx.x; j < HID * HID; j += 256) Ws[j] = W[j];
    __syncthreads();
    const int lane = threadIdx.x & 63;
    const int wib  = threadIdx.x >> 6;
    const int nw   = (gridDim.x * 256) >> 6;
    const float ep1 = 1.f + eps[li];
    const float bv  = b[lane];
    float lsum = 0.f, lsq = 0.f;
    for (int n = (blockIdx.x * 256 + threadIdx.x) >> 6; n < NN; n += nw){
        float inval = fmaf(ep1, h[n * CAT + lane], agg[n * HID + lane]);
        float acc = bv;
        #pragma unroll
        for (int k = 0; k < HID; ++k)
            acc = fmaf(__shfl(inval, k), Ws[k * HID + lane], acc);
        z1[n * HID + lane] = acc;
        lsum += acc; lsq += acc * acc;
    }
    red[0][wib][lane] = lsum; red[1][wib][lane] = lsq;
    __syncthreads();
    if (threadIdx.x < HID){
        float s = 0.f, q = 0.f;
        #pragma unroll
        for (int t = 0; t < 4; ++t){ s += red[0][t][threadIdx.x]; q += red[1][t][threadIdx.x]; }
        atomicAdd(&stats[threadIdx.x], s);
        atomicAdd(&stats[HID + threadIdx.x], q);
    }
}

// ---- fold BN stats into per-feature scale/shift: a = g*rsqrt(var+eps), c = b - mean*a ----
__global__ void k_finalize(const float* __restrict__ stats, const float* __restrict__ g,
                           const float* __restrict__ bt, float* __restrict__ ac, int width){
    int f = threadIdx.x;
    if (f >= width) return;
    float mean = stats[f] * (1.f / NN);
    float var  = stats[width + f] * (1.f / NN) - mean * mean;
    float a = g[f] * rsqrtf(var + BNE);
    ac[f] = a;
    ac[width + f] = bt[f] - mean * a;
}

// ---- z2 = lrelu(a1*z1 + c1) @ W2 + b2 (+ optional BN stats) ----
template<int STATS>
__global__ void __launch_bounds__(256) k_mm2(const float* __restrict__ z1,
        const float* __restrict__ ac, const float* __restrict__ W,
        const float* __restrict__ b, float* __restrict__ outp, int ostride,
        float* __restrict__ stats){
    __shared__ float Ws[HID * HID];
    __shared__ float red[2][4][HID];
    for (int j = threadIdx.x; j < HID * HID; j += 256) Ws[j] = W[j];
    __syncthreads();
    const int lane = threadIdx.x & 63;
    const int wib  = threadIdx.x >> 6;
    const int nw   = (gridDim.x * 256) >> 6;
    const float a_l = ac[lane], c_l = ac[HID + lane];
    const float bv  = b[lane];
    float lsum = 0.f, lsq = 0.f;
    for (int n = (blockIdx.x * 256 + threadIdx.x) >> 6; n < NN; n += nw){
        float t = lrelu(fmaf(a_l, z1[n * HID + lane], c_l));
        float acc = bv;
        #pragma unroll
        for (int k = 0; k < HID; ++k)
            acc = fmaf(__shfl(t, k), Ws[k * HID + lane], acc);
        outp[n * ostride + lane] = acc;
        if (STATS){ lsum += acc; lsq += acc * acc; }
    }
    if (STATS){
        red[0][wib][lane] = lsum; red[1][wib][lane] = lsq;
        __syncthreads();
        if (threadIdx.x < HID){
            float s = 0.f, q = 0.f;
            #pragma unroll
            for (int t = 0; t < 4; ++t){ s += red[0][t][threadIdx.x]; q += red[1][t][threadIdx.x]; }
            atomicAdd(&stats[threadIdx.x], s);
            atomicAdd(&stats[HID + threadIdx.x], q);
        }
    }
}

// ---- xs[:, off] = lrelu(a*z2 + c) ----
__global__ void __launch_bounds__(256) k_apply(const float* __restrict__ z2,
        const float* __restrict__ ac, float* __restrict__ dst){
    int idx = blockIdx.x * 256 + threadIdx.x;            // over NN*64
    if (idx >= NN * HID) return;
    int n = idx >> 6, f = idx & 63;
    dst[n * CAT + f] = lrelu(fmaf(ac[f], z2[idx], ac[HID + f]));
}

// ---- o1 = xs @ Wc1 + bc1 (N x 256 @ 256 x 128), accumulate BN stats ----
// block: 32 nodes, 256 threads, thread = 4 nodes x 4 features
__global__ void __launch_bounds__(256) k_mmc1(const float* __restrict__ xs,
        const f4* __restrict__ Wc14, const float* __restrict__ bc1,
        float* __restrict__ o1, float* __restrict__ stats){
    __shared__ float ins[32 * CAT];    // 32 KB
    __shared__ float Ws[64 * MID];     // 32 KB
    const int tid = threadIdx.x;
    const int nb  = blockIdx.x * 32;
    {
        const f4* src = (const f4*)xs + (size_t)nb * (CAT / 4);
        f4* dst = (f4*)ins;
        for (int j = tid; j < 32 * CAT / 4; j += 256) dst[j] = src[j];
    }
    const int fb = (tid & 31) * 4;     // feature base
    const int ng = tid >> 5;           // node sub-group 0..7
    float acc[4][4];
    #pragma unroll
    for (int j = 0; j < 4; ++j){ acc[j][0]=0.f; acc[j][1]=0.f; acc[j][2]=0.f; acc[j][3]=0.f; }
    for (int c = 0; c < 4; ++c){
        __syncthreads();
        f4* wd = (f4*)Ws;
        for (int j = tid; j < 2048; j += 256) wd[j] = Wc14[c * 2048 + j];
        __syncthreads();
        const float* i0 = ins + (ng +  0) * CAT + c * 64;
        const float* i1 = ins + (ng +  8) * CAT + c * 64;
        const float* i2 = ins + (ng + 16) * CAT + c * 64;
        const float* i3 = ins + (ng + 24) * CAT + c * 64;
        #pragma unroll 8
        for (int k = 0; k < 64; ++k){
            f4 wv = *(const f4*)&Ws[k * MID + fb];
            float v0 = i0[k], v1 = i1[k], v2 = i2[k], v3 = i3[k];
            acc[0][0]=fmaf(v0,wv.x,acc[0][0]); acc[0][1]=fmaf(v0,wv.y,acc[0][1]); acc[0][2]=fmaf(v0,wv.z,acc[0][2]); acc[0][3]=fmaf(v0,wv.w,acc[0][3]);
            acc[1][0]=fmaf(v1,wv.x,acc[1][0]); acc[1][1]=fmaf(v1,wv.y,acc[1][1]); acc[1][2]=fmaf(v1,wv.z,acc[1][2]); acc[1][3]=fmaf(v1,wv.w,acc[1][3]);
            acc[2][0]=fmaf(v2,wv.x,acc[2][0]); acc[2][1]=fmaf(v2,wv.y,acc[2][1]); acc[2][2]=fmaf(v2,wv.z,acc[2][2]); acc[2][3]=fmaf(v2,wv.w,acc[2][3]);
            acc[3][0]=fmaf(v3,wv.x,acc[3][0]); acc[3][1]=fmaf(v3,wv.y,acc[3][1]); acc[3][2]=fmaf(v3,wv.z,acc[3][2]); acc[3][3]=fmaf(v3,wv.w,acc[3][3]);
        }
    }
    __syncthreads();
    float* reds = ins;                 // reuse LDS for stats reduce (256 floats)
    reds[tid] = 0.f;
    __syncthreads();
    f4 bb = *(const f4*)&bc1[fb];
    float s[4] = {0,0,0,0}, q[4] = {0,0,0,0};
    #pragma unroll
    for (int j = 0; j < 4; ++j){
        int n = nb + ng + 8 * j;
        f4 o;
        o.x = acc[j][0] + bb.x; o.y = acc[j][1] + bb.y;
        o.z = acc[j][2] + bb.z; o.w = acc[j][3] + bb.w;
        *(f4*)&o1[(size_t)n * MID + fb] = o;
        s[0]+=o.x; s[1]+=o.y; s[2]+=o.z; s[3]+=o.w;
        q[0]+=o.x*o.x; q[1]+=o.y*o.y; q[2]+=o.z*o.z; q[3]+=o.w*o.w;
    }
    #pragma unroll
    for (int c2 = 0; c2 < 4; ++c2){
        atomicAdd(&reds[fb + c2], s[c2]);
        atomicAdd(&reds[MID + fb + c2], q[c2]);
    }
    __syncthreads();
    atomicAdd(&stats[tid], reds[tid]);  // tid<256 covers sum[128]+sq[128]
}

// ---- out[n] = lrelu(aC*o1 + cC) . Wc2 + bc2 ----
__global__ void __launch_bounds__(256) k_final(const float* __restrict__ o1,
        const float* __restrict__ acC, const float* __restrict__ Wc2,
        const float* __restrict__ bc2, float* __restrict__ out){
    const int lane = threadIdx.x & 63;
    const int nw   = (gridDim.x * 256) >> 6;
    const float a0 = acC[lane],      c0 = acC[MID + lane];
    const float a1 = acC[64 + lane], c1 = acC[MID + 64 + lane];
    const float w0 = Wc2[lane], w1 = Wc2[64 + lane];
    const float bb = bc2[0];
    for (int n = (blockIdx.x * 256 + threadIdx.x) >> 6; n < NN; n += nw){
        float t0 = lrelu(fmaf(a0, o1[(size_t)n * MID + lane], c0));
        float t1 = lrelu(fmaf(a1, o1[(size_t)n * MID + 64 + lane], c1));
        float s = fmaf(t0, w0, t1 * w1);
        #pragma unroll
        for (int m = 32; m > 0; m >>= 1) s += __shfl_xor(s, m);
        if (lane == 0) out[n] = s + bb;
    }
}

extern "C" void kernel_launch(void* const* d_in, const int* in_sizes, int n_in,
                              void* d_out, int out_size, void* d_ws, size_t ws_size,
                              hipStream_t stream){
    (void)in_sizes; (void)n_in; (void)out_size; (void)ws_size;
    const float* x   = (const float*)d_in[0];
    const int*   ei  = (const int*)  d_in[1];
    const float* ea  = (const float*)d_in[2];
    const float* eps = (const float*)d_in[3];
    const float* We  = (const float*)d_in[4];
    const float* be  = (const float*)d_in[5];
    const float* W1  = (const float*)d_in[6];
    const float* b1  = (const float*)d_in[7];
    const float* g1  = (const float*)d_in[8];
    const float* bt1 = (const float*)d_in[9];
    const float* W2  = (const float*)d_in[10];
    const float* b2  = (const float*)d_in[11];
    const float* bng = (const float*)d_in[12];
    const float* bnb = (const float*)d_in[13];
    const float* Wc1 = (const float*)d_in[14];
    const float* bc1 = (const float*)d_in[15];
    const float* gc  = (const float*)d_in[16];
    const float* btc = (const float*)d_in[17];
    const float* Wc2 = (const float*)d_in[18];
    const float* bc2 = (const float*)d_in[19];
    float* out = (float*)d_out;
    float* ws  = (float*)d_ws;

    float* xs    = ws;                             // NN*256
    float* agg   = xs  + (size_t)NN * CAT;         // NN*64
    float* z1    = agg + (size_t)NN * HID;         // NN*64
    float* z2    = z1  + (size_t)NN * HID;         // NN*64
    float* stats = z2  + (size_t)NN * HID;         // 256
    float* ac1   = stats + 256;                    // 128
    float* ac2   = ac1 + 128;                      // 128
    float* acC   = ac2 + 128;                      // 256
    float* o1    = agg;                            // reuse agg+z1 (NN*128)

    k_copy_x<<<6250, 256, 0, stream>>>((const f4*)x, (f4*)xs);

    for (int i = 0; i < 3; ++i){
        hipMemsetAsync(agg, 0, (size_t)NN * HID * sizeof(float), stream);
        hipMemsetAsync(stats, 0, 256 * sizeof(float), stream);
        k_edge<<<4096, 256, 0, stream>>>(xs + i * HID, ei, (const f4*)ea,
                                         We + i * FE * HID, be + i * HID, agg);
        k_mm1<<<2048, 256, 0, stream>>>(xs + i * HID, agg, eps, i,
                                        W1 + i * HID * HID, b1 + i * HID, z1, stats);
        k_finalize<<<1, 64, 0, stream>>>(stats, g1 + i * HID, bt1 + i * HID, ac1, HID);
        if (i < 2){
            k_mm2<1><<<2048, 256, 0, stream>>>(z1, ac1, W2 + i * HID * HID, b2 + i * HID,
                                               z2, HID, stats + 128);
            k_finalize<<<1, 64, 0, stream>>>(stats + 128, bng + i * HID, bnb + i * HID, ac2, HID);
            k_apply<<<25000, 256, 0, stream>>>(z2, ac2, xs + (i + 1) * HID);
        } else {
            k_mm2<0><<<2048, 256, 0, stream>>>(z1, ac1, W2 + i * HID * HID, b2 + i * HID,
                                               xs + (i + 1) * HID, CAT, nullptr);
        }
    }

    hipMemsetAsync(stats, 0, 256 * sizeof(float), stream);
    k_mmc1<<<3125, 256, 0, stream>>>(xs, (const f4*)Wc1, bc1, o1, stats);
    k_finalize<<<1, 128, 0, stream>>>(stats, gc, btc, acC, MID);
    k_final<<<6250, 256, 0, stream>>>(o1, acC, Wc2, bc2, out);
}

// Round 8
// 1759.779 us; speedup vs baseline: 1.1528x; 1.1528x over previous
//
#include <hip/hip_runtime.h>

#define NN   100000
#define NE   1600000
#define FE   16
#define HID  64
#define MID  128
#define CAT  256
#define LEAK 0.01f
#define BNE  1e-5f
#define NT   98            // scan tiles: ceil(NN/1024)

typedef float4 f4;

__device__ __forceinline__ float lrelu(float v){ return v >= 0.f ? v : LEAK * v; }

// ---- copy x into xs[:, 0:64] (xs row stride 256 floats) ----
__global__ void __launch_bounds__(256) k_copy_x(const f4* __restrict__ x4, f4* __restrict__ xs4){
    int idx = blockIdx.x * 256 + threadIdx.x;            // over NN*16 float4s
    if (idx >= NN * 16) return;
    int n = idx >> 4, j = idx & 15;
    xs4[n * 64 + j] = x4[idx];
}

// ==================== CSR build (once per call, reused by 3 layers) ====================

// deg[dst]++ over all edges
__global__ void __launch_bounds__(256) k_count(const int* __restrict__ ei, int* __restrict__ deg){
    const int stride = gridDim.x * 256;
    for (int e = blockIdx.x * 256 + threadIdx.x; e < NE; e += stride)
        atomicAdd(&deg[ei[NE + e]], 1);
}

// per-tile exclusive scan (tile = 1024 elements, 256 thr x 4), block totals -> aux
__global__ void __launch_bounds__(256) k_scan1(const int* __restrict__ deg,
        int* __restrict__ roff, int* __restrict__ aux){
    __shared__ int sh[256];
    const int tid = threadIdx.x;
    const int base = blockIdx.x * 1024 + tid * 4;
    int e[4], s = 0;
    #pragma unroll
    for (int j = 0; j < 4; ++j){ int i = base + j; e[j] = (i < NN) ? deg[i] : 0; s += e[j]; }
    sh[tid] = s; __syncthreads();
    for (int off = 1; off < 256; off <<= 1){
        int cur = sh[tid]; int add = (tid >= off) ? sh[tid - off] : 0;
        __syncthreads(); sh[tid] = cur + add; __syncthreads();
    }
    int run = sh[tid] - s;           // exclusive
    #pragma unroll
    for (int j = 0; j < 4; ++j){ int i = base + j; if (i < NN) roff[i] = run; run += e[j]; }
    if (tid == 255) aux[blockIdx.x] = sh[255];
}

// exclusive scan of aux[NT], total -> aux[NT]
__global__ void __launch_bounds__(128) k_scan2(int* __restrict__ aux){
    __shared__ int sh[128];
    const int tid = threadIdx.x;
    int v = (tid < NT) ? aux[tid] : 0;
    sh[tid] = v; __syncthreads();
    for (int off = 1; off < 128; off <<= 1){
        int cur = sh[tid]; int add = (tid >= off) ? sh[tid - off] : 0;
        __syncthreads(); sh[tid] = cur + add; __syncthreads();
    }
    if (tid < NT) aux[tid] = sh[tid] - v;
    if (tid == 0) aux[NT] = sh[127];
}

// add tile offsets; write roff[NN] = total
__global__ void __launch_bounds__(256) k_scan3(int* __restrict__ roff, const int* __restrict__ aux){
    int idx = blockIdx.x * 256 + threadIdx.x;
    if (idx < NN) roff[idx] += aux[idx >> 10];
    if (idx == 0) roff[NN] = aux[NT];
}

// scatter edges into dst-sorted order: src ids + permuted edge_attr rows
__global__ void __launch_bounds__(256) k_scatter(const int* __restrict__ ei,
        const f4* __restrict__ ea4, int* __restrict__ rcur,
        int* __restrict__ ssrc, f4* __restrict__ ea_s){
    const int stride = gridDim.x * 256;
    for (int e = blockIdx.x * 256 + threadIdx.x; e < NE; e += stride){
        int dst = ei[NE + e];
        int pos = atomicAdd(&rcur[dst], 1);
        ssrc[pos] = ei[e];
        f4 a = ea4[e * 4 + 0], b = ea4[e * 4 + 1], c = ea4[e * 4 + 2], d = ea4[e * 4 + 3];
        ea_s[pos * 4 + 0] = a; ea_s[pos * 4 + 1] = b;
        ea_s[pos * 4 + 2] = c; ea_s[pos * 4 + 3] = d;
    }
}

// ---- per-layer aggregation, atomic-free: wave per dst node ----
// agg[n] = sum_{p in [roff[n],roff[n+1])} relu(h[ssrc[p]] + ea_s[p] @ We + be)
__global__ void __launch_bounds__(256) k_gather(const float* __restrict__ h,
        const int* __restrict__ roff, const int* __restrict__ ssrc,
        const f4* __restrict__ ea_s, const float* __restrict__ We,
        const float* __restrict__ be, float* __restrict__ agg){
    const int lane = threadIdx.x & 63;
    float w[FE];
    #pragma unroll
    for (int k = 0; k < FE; ++k) w[k] = We[k * HID + lane];
    const float bv = be[lane];
    const int nwav = (gridDim.x * 256) >> 6;
    for (int n = (blockIdx.x * 256 + threadIdx.x) >> 6; n < NN; n += nwav){
        int r0 = roff[n], r1 = roff[n + 1];
        float acc = 0.f;
        for (int p = r0; p < r1; ++p){
            int s = ssrc[p];
            float m = bv;
            f4 v0 = ea_s[p * 4 + 0], v1 = ea_s[p * 4 + 1];
            f4 v2 = ea_s[p * 4 + 2], v3 = ea_s[p * 4 + 3];
            m = fmaf(v0.x, w[ 0], m); m = fmaf(v0.y, w[ 1], m); m = fmaf(v0.z, w[ 2], m); m = fmaf(v0.w, w[ 3], m);
            m = fmaf(v1.x, w[ 4], m); m = fmaf(v1.y, w[ 5], m); m = fmaf(v1.z, w[ 6], m); m = fmaf(v1.w, w[ 7], m);
            m = fmaf(v2.x, w[ 8], m); m = fmaf(v2.y, w[ 9], m); m = fmaf(v2.z, w[10], m); m = fmaf(v2.w, w[11], m);
            m = fmaf(v3.x, w[12], m); m = fmaf(v3.y, w[13], m); m = fmaf(v3.z, w[14], m); m = fmaf(v3.w, w[15], m);
            acc += fmaxf(h[(size_t)s * CAT + lane] + m, 0.f);
        }
        agg[n * HID + lane] = acc;
    }
}

// ==================== node-side ====================

// ---- z1 = ((1+eps)*h + agg) @ W1 + b1, accumulate BN stats ----
__global__ void __launch_bounds__(256) k_mm1(const float* __restrict__ h,
        const float* __restrict__ agg, const float* __restrict__ eps, int li,
        const float* __restrict__ W, const float* __restrict__ b,
        float* __restrict__ z1, float* __restrict__ stats){
    __shared__ float Ws[HID * HID];
    __shared__ float red[2][4][HID];
    for (int j = threadIdx.x; j < HID * HID; j += 256) Ws[j] = W[j];
    __syncthreads();
    const int lane = threadIdx.x & 63;
    const int wib  = threadIdx.x >> 6;
    const int nw   = (gridDim.x * 256) >> 6;
    const float ep1 = 1.f + eps[li];
    const float bv  = b[lane];
    float lsum = 0.f, lsq = 0.f;
    for (int n = (blockIdx.x * 256 + threadIdx.x) >> 6; n < NN; n += nw){
        float inval = fmaf(ep1, h[n * CAT + lane], agg[n * HID + lane]);
        float acc = bv;
        #pragma unroll
        for (int k = 0; k < HID; ++k)
            acc = fmaf(__shfl(inval, k), Ws[k * HID + lane], acc);
        z1[n * HID + lane] = acc;
        lsum += acc; lsq += acc * acc;
    }
    red[0][wib][lane] = lsum; red[1][wib][lane] = lsq;
    __syncthreads();
    if (threadIdx.x < HID){
        float s = 0.f, q = 0.f;
        #pragma unroll
        for (int t = 0; t < 4; ++t){ s += red[0][t][threadIdx.x]; q += red[1][t][threadIdx.x]; }
        atomicAdd(&stats[threadIdx.x], s);
        atomicAdd(&stats[HID + threadIdx.x], q);
    }
}

// ---- fold BN stats: a = g*rsqrt(var+eps), c = b - mean*a ----
__global__ void k_finalize(const float* __restrict__ stats, const float* __restrict__ g,
                           const float* __restrict__ bt, float* __restrict__ ac, int width){
    int f = threadIdx.x;
    if (f >= width) return;
    float mean = stats[f] * (1.f / NN);
    float var  = stats[width + f] * (1.f / NN) - mean * mean;
    float a = g[f] * rsqrtf(var + BNE);
    ac[f] = a;
    ac[width + f] = bt[f] - mean * a;
}

// ---- z2 = lrelu(a1*z1 + c1) @ W2 + b2 (+ optional BN stats) ----
template<int STATS>
__global__ void __launch_bounds__(256) k_mm2(const float* __restrict__ z1,
        const float* __restrict__ ac, const float* __restrict__ W,
        const float* __restrict__ b, float* __restrict__ outp, int ostride,
        float* __restrict__ stats){
    __shared__ float Ws[HID * HID];
    __shared__ float red[2][4][HID];
    for (int j = threadIdx.x; j < HID * HID; j += 256) Ws[j] = W[j];
    __syncthreads();
    const int lane = threadIdx.x & 63;
    const int wib  = threadIdx.x >> 6;
    const int nw   = (gridDim.x * 256) >> 6;
    const float a_l = ac[lane], c_l = ac[HID + lane];
    const float bv  = b[lane];
    float lsum = 0.f, lsq = 0.f;
    for (int n = (blockIdx.x * 256 + threadIdx.x) >> 6; n < NN; n += nw){
        float t = lrelu(fmaf(a_l, z1[n * HID + lane], c_l));
        float acc = bv;
        #pragma unroll
        for (int k = 0; k < HID; ++k)
            acc = fmaf(__shfl(t, k), Ws[k * HID + lane], acc);
        outp[n * ostride + lane] = acc;
        if (STATS){ lsum += acc; lsq += acc * acc; }
    }
    if (STATS){
        red[0][wib][lane] = lsum; red[1][wib][lane] = lsq;
        __syncthreads();
        if (threadIdx.x < HID){
            float s = 0.f, q = 0.f;
            #pragma unroll
            for (int t = 0; t < 4; ++t){ s += red[0][t][threadIdx.x]; q += red[1][t][threadIdx.x]; }
            atomicAdd(&stats[threadIdx.x], s);
            atomicAdd(&stats[HID + threadIdx.x], q);
        }
    }
}

// ---- xs[:, off] = lrelu(a*z2 + c) ----
__global__ void __launch_bounds__(256) k_apply(const float* __restrict__ z2,
        const float* __restrict__ ac, float* __restrict__ dst){
    int idx = blockIdx.x * 256 + threadIdx.x;            // over NN*64
    if (idx >= NN * HID) return;
    int n = idx >> 6, f = idx & 63;
    dst[n * CAT + f] = lrelu(fmaf(ac[f], z2[idx], ac[HID + f]));
}

// ---- o1 = xs @ Wc1 + bc1 (N x 256 @ 256 x 128), accumulate BN stats ----
__global__ void __launch_bounds__(256) k_mmc1(const float* __restrict__ xs,
        const f4* __restrict__ Wc14, const float* __restrict__ bc1,
        float* __restrict__ o1, float* __restrict__ stats){
    __shared__ float ins[32 * CAT];    // 32 KB
    __shared__ float Ws[64 * MID];     // 32 KB
    const int tid = threadIdx.x;
    const int nb  = blockIdx.x * 32;
    {
        const f4* src = (const f4*)xs + (size_t)nb * (CAT / 4);
        f4* dst = (f4*)ins;
        for (int j = tid; j < 32 * CAT / 4; j += 256) dst[j] = src[j];
    }
    const int fb = (tid & 31) * 4;     // feature base
    const int ng = tid >> 5;           // node sub-group 0..7
    float acc[4][4];
    #pragma unroll
    for (int j = 0; j < 4; ++j){ acc[j][0]=0.f; acc[j][1]=0.f; acc[j][2]=0.f; acc[j][3]=0.f; }
    for (int c = 0; c < 4; ++c){
        __syncthreads();
        f4* wd = (f4*)Ws;
        for (int j = tid; j < 2048; j += 256) wd[j] = Wc14[c * 2048 + j];
        __syncthreads();
        const float* i0 = ins + (ng +  0) * CAT + c * 64;
        const float* i1 = ins + (ng +  8) * CAT + c * 64;
        const float* i2 = ins + (ng + 16) * CAT + c * 64;
        const float* i3 = ins + (ng + 24) * CAT + c * 64;
        #pragma unroll 8
        for (int k = 0; k < 64; ++k){
            f4 wv = *(const f4*)&Ws[k * MID + fb];
            float v0 = i0[k], v1 = i1[k], v2 = i2[k], v3 = i3[k];
            acc[0][0]=fmaf(v0,wv.x,acc[0][0]); acc[0][1]=fmaf(v0,wv.y,acc[0][1]); acc[0][2]=fmaf(v0,wv.z,acc[0][2]); acc[0][3]=fmaf(v0,wv.w,acc[0][3]);
            acc[1][0]=fmaf(v1,wv.x,acc[1][0]); acc[1][1]=fmaf(v1,wv.y,acc[1][1]); acc[1][2]=fmaf(v1,wv.z,acc[1][2]); acc[1][3]=fmaf(v1,wv.w,acc[1][3]);
            acc[2][0]=fmaf(v2,wv.x,acc[2][0]); acc[2][1]=fmaf(v2,wv.y,acc[2][1]); acc[2][2]=fmaf(v2,wv.z,acc[2][2]); acc[2][3]=fmaf(v2,wv.w,acc[2][3]);
            acc[3][0]=fmaf(v3,wv.x,acc[3][0]); acc[3][1]=fmaf(v3,wv.y,acc[3][1]); acc[3][2]=fmaf(v3,wv.z,acc[3][2]); acc[3][3]=fmaf(v3,wv.w,acc[3][3]);
        }
    }
    __syncthreads();
    float* reds = ins;                 // reuse LDS for stats reduce (256 floats)
    reds[tid] = 0.f;
    __syncthreads();
    f4 bb = *(const f4*)&bc1[fb];
    float s[4] = {0,0,0,0}, q[4] = {0,0,0,0};
    #pragma unroll
    for (int j = 0; j < 4; ++j){
        int n = nb + ng + 8 * j;
        f4 o;
        o.x = acc[j][0] + bb.x; o.y = acc[j][1] + bb.y;
        o.z = acc[j][2] + bb.z; o.w = acc[j][3] + bb.w;
        *(f4*)&o1[(size_t)n * MID + fb] = o;
        s[0]+=o.x; s[1]+=o.y; s[2]+=o.z; s[3]+=o.w;
        q[0]+=o.x*o.x; q[1]+=o.y*o.y; q[2]+=o.z*o.z; q[3]+=o.w*o.w;
    }
    #pragma unroll
    for (int c2 = 0; c2 < 4; ++c2){
        atomicAdd(&reds[fb + c2], s[c2]);
        atomicAdd(&reds[MID + fb + c2], q[c2]);
    }
    __syncthreads();
    atomicAdd(&stats[tid], reds[tid]);
}

// ---- out[n] = lrelu(aC*o1 + cC) . Wc2 + bc2 ----
__global__ void __launch_bounds__(256) k_final(const float* __restrict__ o1,
        const float* __restrict__ acC, const float* __restrict__ Wc2,
        const float* __restrict__ bc2, float* __restrict__ out){
    const int lane = threadIdx.x & 63;
    const int nw   = (gridDim.x * 256) >> 6;
    const float a0 = acC[lane],      c0 = acC[MID + lane];
    const float a1 = acC[64 + lane], c1 = acC[MID + 64 + lane];
    const float w0 = Wc2[lane], w1 = Wc2[64 + lane];
    const float bb = bc2[0];
    for (int n = (blockIdx.x * 256 + threadIdx.x) >> 6; n < NN; n += nw){
        float t0 = lrelu(fmaf(a0, o1[(size_t)n * MID + lane], c0));
        float t1 = lrelu(fmaf(a1, o1[(size_t)n * MID + 64 + lane], c1));
        float s = fmaf(t0, w0, t1 * w1);
        #pragma unroll
        for (int m = 32; m > 0; m >>= 1) s += __shfl_xor(s, m);
        if (lane == 0) out[n] = s + bb;
    }
}

extern "C" void kernel_launch(void* const* d_in, const int* in_sizes, int n_in,
                              void* d_out, int out_size, void* d_ws, size_t ws_size,
                              hipStream_t stream){
    (void)in_sizes; (void)n_in; (void)out_size; (void)ws_size;
    const float* x   = (const float*)d_in[0];
    const int*   ei  = (const int*)  d_in[1];
    const float* ea  = (const float*)d_in[2];
    const float* eps = (const float*)d_in[3];
    const float* We  = (const float*)d_in[4];
    const float* be  = (const float*)d_in[5];
    const float* W1  = (const float*)d_in[6];
    const float* b1  = (const float*)d_in[7];
    const float* g1  = (const float*)d_in[8];
    const float* bt1 = (const float*)d_in[9];
    const float* W2  = (const float*)d_in[10];
    const float* b2  = (const float*)d_in[11];
    const float* bng = (const float*)d_in[12];
    const float* bnb = (const float*)d_in[13];
    const float* Wc1 = (const float*)d_in[14];
    const float* bc1 = (const float*)d_in[15];
    const float* gc  = (const float*)d_in[16];
    const float* btc = (const float*)d_in[17];
    const float* Wc2 = (const float*)d_in[18];
    const float* bc2 = (const float*)d_in[19];
    float* out = (float*)d_out;
    float* ws  = (float*)d_ws;

    // ---- workspace layout (≈263 MB) ----
    float* xs    = ws;                             // NN*256
    float* agg   = xs  + (size_t)NN * CAT;         // NN*64
    float* z1    = agg + (size_t)NN * HID;         // NN*64
    float* stats = z1  + (size_t)NN * HID;         // 256
    float* ac1   = stats + 256;                    // 128
    float* ac2   = ac1 + 128;                      // 128
    float* acC   = ac2 + 128;                      // 256
    int*   roff  = (int*)(acC + 256);              // NN+1 (pad to 100004)
    int*   aux   = roff + 100004;                  // NT+1 (pad to 128)
    int*   rcur  = aux + 128;                      // NN (also deg during count)
    int*   ssrc  = rcur + NN;                      // NE
    f4*    ea_s  = (f4*)(ssrc + NE);               // NE*16 floats (16B-aligned)
    float* z2    = agg;                            // alias: agg dead once k_mm1 ran
    float* o1    = agg;                            // alias: agg+z1 span (NN*128), used after layers

    // ---- build CSR (dst-sorted edges), reused by all 3 layers ----
    hipMemsetAsync(rcur, 0, NN * sizeof(int), stream);
    k_count  <<<2048, 256, 0, stream>>>(ei, rcur);
    k_scan1  <<<NT,   256, 0, stream>>>(rcur, roff, aux);
    k_scan2  <<<1,    128, 0, stream>>>(aux);
    k_scan3  <<<391,  256, 0, stream>>>(roff, aux);
    hipMemcpyAsync(rcur, roff, NN * sizeof(int), hipMemcpyDeviceToDevice, stream);
    k_scatter<<<2048, 256, 0, stream>>>(ei, (const f4*)ea, rcur, ssrc, ea_s);

    k_copy_x<<<6250, 256, 0, stream>>>((const f4*)x, (f4*)xs);

    for (int i = 0; i < 3; ++i){
        hipMemsetAsync(stats, 0, 256 * sizeof(float), stream);
        k_gather<<<2048, 256, 0, stream>>>(xs + i * HID, roff, ssrc, ea_s,
                                           We + i * FE * HID, be + i * HID, agg);
        k_mm1<<<2048, 256, 0, stream>>>(xs + i * HID, agg, eps, i,
                                        W1 + i * HID * HID, b1 + i * HID, z1, stats);
        k_finalize<<<1, 64, 0, stream>>>(stats, g1 + i * HID, bt1 + i * HID, ac1, HID);
        if (i < 2){
            k_mm2<1><<<2048, 256, 0, stream>>>(z1, ac1, W2 + i * HID * HID, b2 + i * HID,
                                               z2, HID, stats + 128);
            k_finalize<<<1, 64, 0, stream>>>(stats + 128, bng + i * HID, bnb + i * HID, ac2, HID);
            k_apply<<<25000, 256, 0, stream>>>(z2, ac2, xs + (i + 1) * HID);
        } else {
            k_mm2<0><<<2048, 256, 0, stream>>>(z1, ac1, W2 + i * HID * HID, b2 + i * HID,
                                               xs + (i + 1) * HID, CAT, nullptr);
        }
    }

    hipMemsetAsync(stats, 0, 256 * sizeof(float), stream);
    k_mmc1<<<3125, 256, 0, stream>>>(xs, (const f4*)Wc1, bc1, o1, stats);
    k_finalize<<<1, 128, 0, stream>>>(stats, gc, btc, acC, MID);
    k_final<<<6250, 256, 0, stream>>>(o1, acC, Wc2, bc2, out);
}

// Round 10
// 1497.358 us; speedup vs baseline: 1.3548x; 1.1753x over previous
//
#include <hip/hip_runtime.h>

#define NN   100000
#define NE   1600000
#define FE   16
#define HID  64
#define MID  128
#define CAT  256
#define LEAK 0.01f
#define BNE  1e-5f
#define NT   98            // scan tiles: ceil(NN/1024)

typedef float4 f4;

__device__ __forceinline__ float lrelu(float v){ return v >= 0.f ? v : LEAK * v; }

// ---- copy x into xs[:, 0:64] (xs row stride 256 floats) ----
__global__ void __launch_bounds__(256) k_copy_x(const f4* __restrict__ x4, f4* __restrict__ xs4){
    int idx = blockIdx.x * 256 + threadIdx.x;            // over NN*16 float4s
    if (idx >= NN * 16) return;
    int n = idx >> 4, j = idx & 15;
    xs4[n * 64 + j] = x4[idx];
}

// ==================== CSR build (once per call, reused by 3 layers) ====================

// deg[dst]++ over all edges
__global__ void __launch_bounds__(256) k_count(const int* __restrict__ ei, int* __restrict__ deg){
    const int stride = gridDim.x * 256;
    for (int e = blockIdx.x * 256 + threadIdx.x; e < NE; e += stride)
        atomicAdd(&deg[ei[NE + e]], 1);
}

// per-tile exclusive scan (tile = 1024 elements, 256 thr x 4), block totals -> aux
__global__ void __launch_bounds__(256) k_scan1(const int* __restrict__ deg,
        int* __restrict__ roff, int* __restrict__ aux){
    __shared__ int sh[256];
    const int tid = threadIdx.x;
    const int base = blockIdx.x * 1024 + tid * 4;
    int e[4], s = 0;
    #pragma unroll
    for (int j = 0; j < 4; ++j){ int i = base + j; e[j] = (i < NN) ? deg[i] : 0; s += e[j]; }
    sh[tid] = s; __syncthreads();
    for (int off = 1; off < 256; off <<= 1){
        int cur = sh[tid]; int add = (tid >= off) ? sh[tid - off] : 0;
        __syncthreads(); sh[tid] = cur + add; __syncthreads();
    }
    int run = sh[tid] - s;           // exclusive
    #pragma unroll
    for (int j = 0; j < 4; ++j){ int i = base + j; if (i < NN) roff[i] = run; run += e[j]; }
    if (tid == 255) aux[blockIdx.x] = sh[255];
}

// exclusive scan of aux[NT], total -> aux[NT]
__global__ void __launch_bounds__(128) k_scan2(int* __restrict__ aux){
    __shared__ int sh[128];
    const int tid = threadIdx.x;
    int v = (tid < NT) ? aux[tid] : 0;
    sh[tid] = v; __syncthreads();
    for (int off = 1; off < 128; off <<= 1){
        int cur = sh[tid]; int add = (tid >= off) ? sh[tid - off] : 0;
        __syncthreads(); sh[tid] = cur + add; __syncthreads();
    }
    if (tid < NT) aux[tid] = sh[tid] - v;
    if (tid == 0) aux[NT] = sh[127];
}

// add tile offsets; write roff[NN] = total
__global__ void __launch_bounds__(256) k_scan3(int* __restrict__ roff, const int* __restrict__ aux){
    int idx = blockIdx.x * 256 + threadIdx.x;
    if (idx < NN) roff[idx] += aux[idx >> 10];
    if (idx == 0) roff[NN] = aux[NT];
}

// scatter (src, edge_id) pairs into dst-sorted order (edge_attr stays in place)
__global__ void __launch_bounds__(256) k_scatter(const int* __restrict__ ei,
        int* __restrict__ rcur, int2* __restrict__ pairs){
    const int stride = gridDim.x * 256;
    for (int e = blockIdx.x * 256 + threadIdx.x; e < NE; e += stride){
        int dst = ei[NE + e];
        int pos = atomicAdd(&rcur[dst], 1);
        pairs[pos] = make_int2(ei[e], e);
    }
}

// edge projection: ea[eid] @ We + be for this lane's output feature
__device__ __forceinline__ float edot(const f4* __restrict__ e, const float* w, float bv){
    f4 v0 = e[0], v1 = e[1], v2 = e[2], v3 = e[3];
    float m = bv;
    m = fmaf(v0.x, w[ 0], m); m = fmaf(v0.y, w[ 1], m); m = fmaf(v0.z, w[ 2], m); m = fmaf(v0.w, w[ 3], m);
    m = fmaf(v1.x, w[ 4], m); m = fmaf(v1.y, w[ 5], m); m = fmaf(v1.z, w[ 6], m); m = fmaf(v1.w, w[ 7], m);
    m = fmaf(v2.x, w[ 8], m); m = fmaf(v2.y, w[ 9], m); m = fmaf(v2.z, w[10], m); m = fmaf(v2.w, w[11], m);
    m = fmaf(v3.x, w[12], m); m = fmaf(v3.y, w[13], m); m = fmaf(v3.z, w[14], m); m = fmaf(v3.w, w[15], m);
    return m;
}

// ---- per-layer aggregation, atomic-free: wave per dst node ----
// agg[n] = sum_p relu(h[src_p] + ea[eid_p] @ We + be)
// All wave-uniform values forced to SGPRs via readfirstlane -> scalar loads
// for pairs/ea rows; only the h gather uses the vector-memory pipe.
__global__ void __launch_bounds__(256) k_gather(const float* __restrict__ h,
        const int* __restrict__ roff, const int2* __restrict__ pairs,
        const f4* __restrict__ ea4, const float* __restrict__ We,
        const float* __restrict__ be, float* __restrict__ agg){
    const int lane = threadIdx.x & 63;
    float w[FE];
    #pragma unroll
    for (int k = 0; k < FE; ++k) w[k] = We[k * HID + lane];
    const float bv = be[lane];
    const int nwav = (gridDim.x * 256) >> 6;
    for (int n = (blockIdx.x * 256 + threadIdx.x) >> 6; n < NN; n += nwav){
        const int nu = __builtin_amdgcn_readfirstlane(n);
        const int r0 = roff[nu], r1 = roff[nu + 1];
        float acc = 0.f;
        int p = r0;
        // 2 edges per iteration: doubles independent loads in flight
        for (; p + 1 < r1; p += 2){
            int2 pr0 = pairs[p];
            int2 pr1 = pairs[p + 1];
            float h0 = h[(size_t)pr0.x * CAT + lane];
            float h1 = h[(size_t)pr1.x * CAT + lane];
            float m0 = edot(ea4 + (size_t)pr0.y * 4, w, bv);
            float m1 = edot(ea4 + (size_t)pr1.y * 4, w, bv);
            acc += fmaxf(h0 + m0, 0.f);
            acc += fmaxf(h1 + m1, 0.f);
        }
        if (p < r1){
            int2 pr = pairs[p];
            float hv = h[(size_t)pr.x * CAT + lane];
            float m  = edot(ea4 + (size_t)pr.y * 4, w, bv);
            acc += fmaxf(hv + m, 0.f);
        }
        agg[nu * HID + lane] = acc;
    }
}

// ==================== node-side ====================

// ---- z1 = ((1+eps)*h + agg) @ W1 + b1, accumulate BN stats ----
__global__ void __launch_bounds__(256) k_mm1(const float* __restrict__ h,
        const float* __restrict__ agg, const float* __restrict__ eps, int li,
        const float* __restrict__ W, const float* __restrict__ b,
        float* __restrict__ z1, float* __restrict__ stats){
    __shared__ float Ws[HID * HID];
    __shared__ float red[2][4][HID];
    for (int j = threadIdx.x; j < HID * HID; j += 256) Ws[j] = W[j];
    __syncthreads();
    const int lane = threadIdx.x & 63;
    const int wib  = threadIdx.x >> 6;
    const int nw   = (gridDim.x * 256) >> 6;
    const float ep1 = 1.f + eps[li];
    const float bv  = b[lane];
    float lsum = 0.f, lsq = 0.f;
    for (int n = (blockIdx.x * 256 + threadIdx.x) >> 6; n < NN; n += nw){
        float inval = fmaf(ep1, h[n * CAT + lane], agg[n * HID + lane]);
        float acc = bv;
        #pragma unroll
        for (int k = 0; k < HID; ++k)
            acc = fmaf(__shfl(inval, k), Ws[k * HID + lane], acc);
        z1[n * HID + lane] = acc;
        lsum += acc; lsq += acc * acc;
    }
    red[0][wib][lane] = lsum; red[1][wib][lane] = lsq;
    __syncthreads();
    if (threadIdx.x < HID){
        float s = 0.f, q = 0.f;
        #pragma unroll
        for (int t = 0; t < 4; ++t){ s += red[0][t][threadIdx.x]; q += red[1][t][threadIdx.x]; }
        atomicAdd(&stats[threadIdx.x], s);
        atomicAdd(&stats[HID + threadIdx.x], q);
    }
}

// ---- fold BN stats: a = g*rsqrt(var+eps), c = b - mean*a ----
__global__ void k_finalize(const float* __restrict__ stats, const float* __restrict__ g,
                           const float* __restrict__ bt, float* __restrict__ ac, int width){
    int f = threadIdx.x;
    if (f >= width) return;
    float mean = stats[f] * (1.f / NN);
    float var  = stats[width + f] * (1.f / NN) - mean * mean;
    float a = g[f] * rsqrtf(var + BNE);
    ac[f] = a;
    ac[width + f] = bt[f] - mean * a;
}

// ---- z2 = lrelu(a1*z1 + c1) @ W2 + b2 (+ optional BN stats) ----
template<int STATS>
__global__ void __launch_bounds__(256) k_mm2(const float* __restrict__ z1,
        const float* __restrict__ ac, const float* __restrict__ W,
        const float* __restrict__ b, float* __restrict__ outp, int ostride,
        float* __restrict__ stats){
    __shared__ float Ws[HID * HID];
    __shared__ float red[2][4][HID];
    for (int j = threadIdx.x; j < HID * HID; j += 256) Ws[j] = W[j];
    __syncthreads();
    const int lane = threadIdx.x & 63;
    const int wib  = threadIdx.x >> 6;
    const int nw   = (gridDim.x * 256) >> 6;
    const float a_l = ac[lane], c_l = ac[HID + lane];
    const float bv  = b[lane];
    float lsum = 0.f, lsq = 0.f;
    for (int n = (blockIdx.x * 256 + threadIdx.x) >> 6; n < NN; n += nw){
        float t = lrelu(fmaf(a_l, z1[n * HID + lane], c_l));
        float acc = bv;
        #pragma unroll
        for (int k = 0; k < HID; ++k)
            acc = fmaf(__shfl(t, k), Ws[k * HID + lane], acc);
        outp[n * ostride + lane] = acc;
        if (STATS){ lsum += acc; lsq += acc * acc; }
    }
    if (STATS){
        red[0][wib][lane] = lsum; red[1][wib][lane] = lsq;
        __syncthreads();
        if (threadIdx.x < HID){
            float s = 0.f, q = 0.f;
            #pragma unroll
            for (int t = 0; t < 4; ++t){ s += red[0][t][threadIdx.x]; q += red[1][t][threadIdx.x]; }
            atomicAdd(&stats[threadIdx.x], s);
            atomicAdd(&stats[HID + threadIdx.x], q);
        }
    }
}

// ---- xs[:, off] = lrelu(a*z2 + c) ----
__global__ void __launch_bounds__(256) k_apply(const float* __restrict__ z2,
        const float* __restrict__ ac, float* __restrict__ dst){
    int idx = blockIdx.x * 256 + threadIdx.x;            // over NN*64
    if (idx >= NN * HID) return;
    int n = idx >> 6, f = idx & 63;
    dst[n * CAT + f] = lrelu(fmaf(ac[f], z2[idx], ac[HID + f]));
}

// ---- o1 = xs @ Wc1 + bc1 (N x 256 @ 256 x 128), accumulate BN stats ----
__global__ void __launch_bounds__(256) k_mmc1(const float* __restrict__ xs,
        const f4* __restrict__ Wc14, const float* __restrict__ bc1,
        float* __restrict__ o1, float* __restrict__ stats){
    __shared__ float ins[32 * CAT];    // 32 KB
    __shared__ float Ws[64 * MID];     // 32 KB
    const int tid = threadIdx.x;
    const int nb  = blockIdx.x * 32;
    {
        const f4* src = (const f4*)xs + (size_t)nb * (CAT / 4);
        f4* dst = (f4*)ins;
        for (int j = tid; j < 32 * CAT / 4; j += 256) dst[j] = src[j];
    }
    const int fb = (tid & 31) * 4;     // feature base
    const int ng = tid >> 5;           // node sub-group 0..7
    float acc[4][4];
    #pragma unroll
    for (int j = 0; j < 4; ++j){ acc[j][0]=0.f; acc[j][1]=0.f; acc[j][2]=0.f; acc[j][3]=0.f; }
    for (int c = 0; c < 4; ++c){
        __syncthreads();
        f4* wd = (f4*)Ws;
        for (int j = tid; j < 2048; j += 256) wd[j] = Wc14[c * 2048 + j];
        __syncthreads();
        const float* i0 = ins + (ng +  0) * CAT + c * 64;
        const float* i1 = ins + (ng +  8) * CAT + c * 64;
        const float* i2 = ins + (ng + 16) * CAT + c * 64;
        const float* i3 = ins + (ng + 24) * CAT + c * 64;
        #pragma unroll 8
        for (int k = 0; k < 64; ++k){
            f4 wv = *(const f4*)&Ws[k * MID + fb];
            float v0 = i0[k], v1 = i1[k], v2 = i2[k], v3 = i3[k];
            acc[0][0]=fmaf(v0,wv.x,acc[0][0]); acc[0][1]=fmaf(v0,wv.y,acc[0][1]); acc[0][2]=fmaf(v0,wv.z,acc[0][2]); acc[0][3]=fmaf(v0,wv.w,acc[0][3]);
            acc[1][0]=fmaf(v1,wv.x,acc[1][0]); acc[1][1]=fmaf(v1,wv.y,acc[1][1]); acc[1][2]=fmaf(v1,wv.z,acc[1][2]); acc[1][3]=fmaf(v1,wv.w,acc[1][3]);
            acc[2][0]=fmaf(v2,wv.x,acc[2][0]); acc[2][1]=fmaf(v2,wv.y,acc[2][1]); acc[2][2]=fmaf(v2,wv.z,acc[2][2]); acc[2][3]=fmaf(v2,wv.w,acc[2][3]);
            acc[3][0]=fmaf(v3,wv.x,acc[3][0]); acc[3][1]=fmaf(v3,wv.y,acc[3][1]); acc[3][2]=fmaf(v3,wv.z,acc[3][2]); acc[3][3]=fmaf(v3,wv.w,acc[3][3]);
        }
    }
    __syncthreads();
    float* reds = ins;                 // reuse LDS for stats reduce (256 floats)
    reds[tid] = 0.f;
    __syncthreads();
    f4 bb = *(const f4*)&bc1[fb];
    float s[4] = {0,0,0,0}, q[4] = {0,0,0,0};
    #pragma unroll
    for (int j = 0; j < 4; ++j){
        int n = nb + ng + 8 * j;
        f4 o;
        o.x = acc[j][0] + bb.x; o.y = acc[j][1] + bb.y;
        o.z = acc[j][2] + bb.z; o.w = acc[j][3] + bb.w;
        *(f4*)&o1[(size_t)n * MID + fb] = o;
        s[0]+=o.x; s[1]+=o.y; s[2]+=o.z; s[3]+=o.w;
        q[0]+=o.x*o.x; q[1]+=o.y*o.y; q[2]+=o.z*o.z; q[3]+=o.w*o.w;
    }
    #pragma unroll
    for (int c2 = 0; c2 < 4; ++c2){
        atomicAdd(&reds[fb + c2], s[c2]);
        atomicAdd(&reds[MID + fb + c2], q[c2]);
    }
    __syncthreads();
    atomicAdd(&stats[tid], reds[tid]);
}

// ---- out[n] = lrelu(aC*o1 + cC) . Wc2 + bc2 ----
__global__ void __launch_bounds__(256) k_final(const float* __restrict__ o1,
        const float* __restrict__ acC, const float* __restrict__ Wc2,
        const float* __restrict__ bc2, float* __restrict__ out){
    const int lane = threadIdx.x & 63;
    const int nw   = (gridDim.x * 256) >> 6;
    const float a0 = acC[lane],      c0 = acC[MID + lane];
    const float a1 = acC[64 + lane], c1 = acC[MID + 64 + lane];
    const float w0 = Wc2[lane], w1 = Wc2[64 + lane];
    const float bb = bc2[0];
    for (int n = (blockIdx.x * 256 + threadIdx.x) >> 6; n < NN; n += nw){
        float t0 = lrelu(fmaf(a0, o1[(size_t)n * MID + lane], c0));
        float t1 = lrelu(fmaf(a1, o1[(size_t)n * MID + 64 + lane], c1));
        float s = fmaf(t0, w0, t1 * w1);
        #pragma unroll
        for (int m = 32; m > 0; m >>= 1) s += __shfl_xor(s, m);
        if (lane == 0) out[n] = s + bb;
    }
}

extern "C" void kernel_launch(void* const* d_in, const int* in_sizes, int n_in,
                              void* d_out, int out_size, void* d_ws, size_t ws_size,
                              hipStream_t stream){
    (void)in_sizes; (void)n_in; (void)out_size; (void)ws_size;
    const float* x   = (const float*)d_in[0];
    const int*   ei  = (const int*)  d_in[1];
    const float* ea  = (const float*)d_in[2];
    const float* eps = (const float*)d_in[3];
    const float* We  = (const float*)d_in[4];
    const float* be  = (const float*)d_in[5];
    const float* W1  = (const float*)d_in[6];
    const float* b1  = (const float*)d_in[7];
    const float* g1  = (const float*)d_in[8];
    const float* bt1 = (const float*)d_in[9];
    const float* W2  = (const float*)d_in[10];
    const float* b2  = (const float*)d_in[11];
    const float* bng = (const float*)d_in[12];
    const float* bnb = (const float*)d_in[13];
    const float* Wc1 = (const float*)d_in[14];
    const float* bc1 = (const float*)d_in[15];
    const float* gc  = (const float*)d_in[16];
    const float* btc = (const float*)d_in[17];
    const float* Wc2 = (const float*)d_in[18];
    const float* bc2 = (const float*)d_in[19];
    float* out = (float*)d_out;
    float* ws  = (float*)d_ws;

    // ---- workspace layout (≈161 MB) ----
    float* xs    = ws;                             // NN*256
    float* agg   = xs  + (size_t)NN * CAT;         // NN*64
    float* z1    = agg + (size_t)NN * HID;         // NN*64
    float* stats = z1  + (size_t)NN * HID;         // 256
    float* ac1   = stats + 256;                    // 128
    float* ac2   = ac1 + 128;                      // 128
    float* acC   = ac2 + 128;                      // 256
    int*   roff  = (int*)(acC + 256);              // NN+1 (pad to 100004)
    int*   aux   = roff + 100004;                  // NT+1 (pad to 128)
    int*   rcur  = aux + 128;                      // NN (also deg during count)
    int2*  pairs = (int2*)(rcur + NN);             // NE (src, edge_id); 8B-aligned
    float* z2    = agg;                            // alias: agg dead once k_mm1 ran
    float* o1    = agg;                            // alias: agg+z1 span (NN*128), used after layers

    // ---- build CSR (dst-sorted (src,eid) pairs), reused by all 3 layers ----
    hipMemsetAsync(rcur, 0, NN * sizeof(int), stream);
    k_count  <<<2048, 256, 0, stream>>>(ei, rcur);
    k_scan1  <<<NT,   256, 0, stream>>>(rcur, roff, aux);
    k_scan2  <<<1,    128, 0, stream>>>(aux);
    k_scan3  <<<391,  256, 0, stream>>>(roff, aux);
    hipMemcpyAsync(rcur, roff, NN * sizeof(int), hipMemcpyDeviceToDevice, stream);
    k_scatter<<<2048, 256, 0, stream>>>(ei, rcur, pairs);

    k_copy_x<<<6250, 256, 0, stream>>>((const f4*)x, (f4*)xs);

    for (int i = 0; i < 3; ++i){
        hipMemsetAsync(stats, 0, 256 * sizeof(float), stream);
        k_gather<<<2048, 256, 0, stream>>>(xs + i * HID, roff, pairs, (const f4*)ea,
                                           We + i * FE * HID, be + i * HID, agg);
        k_mm1<<<2048, 256, 0, stream>>>(xs + i * HID, agg, eps, i,
                                        W1 + i * HID * HID, b1 + i * HID, z1, stats);
        k_finalize<<<1, 64, 0, stream>>>(stats, g1 + i * HID, bt1 + i * HID, ac1, HID);
        if (i < 2){
            k_mm2<1><<<2048, 256, 0, stream>>>(z1, ac1, W2 + i * HID * HID, b2 + i * HID,
                                               z2, HID, stats + 128);
            k_finalize<<<1, 64, 0, stream>>>(stats + 128, bng + i * HID, bnb + i * HID, ac2, HID);
            k_apply<<<25000, 256, 0, stream>>>(z2, ac2, xs + (i + 1) * HID);
        } else {
            k_mm2<0><<<2048, 256, 0, stream>>>(z1, ac1, W2 + i * HID * HID, b2 + i * HID,
                                               xs + (i + 1) * HID, CAT, nullptr);
        }
    }

    hipMemsetAsync(stats, 0, 256 * sizeof(float), stream);
    k_mmc1<<<3125, 256, 0, stream>>>(xs, (const f4*)Wc1, bc1, o1, stats);
    k_finalize<<<1, 128, 0, stream>>>(stats, gc, btc, acC, MID);
    k_final<<<6250, 256, 0, stream>>>(o1, acC, Wc2, bc2, out);
}